// Round 16
// baseline (75.406 us; speedup 1.0000x reference)
//
#include <hip/hip_runtime.h>
#include <math.h>

#define HW    224
#define IMG   (HW * HW)        // 50176
#define OW    223
#define FLAT  (OW * OW)        // 49729
#define NB    1024
#define NCH   16               // row chunks of 14 (chunk 15: 13 rows)
#define RPC   14

// ---------------------------------------------------------------------------
// Kernel 1: fused conv+sigmoid+embed, affine row-streaming, direct embed_w
// reads. Block = (row chunk, 8 images); wave = 2 images, lane = col-group.
// NCH=16 -> 2048 blocks so occupancy is VGPR-limited (6-8 blocks/CU), not
// grid-limited (round-15 was 1024 = exactly 4/CU).
// ---------------------------------------------------------------------------
#define CONV4(T, BT, TE, BE, A0, A1, A2, A3)                                   \
    {                                                                          \
        float _z0 = w00 * T.x + w01 * T.y + w10 * BT.x + w11 * BT.y + cb;      \
        float _z1 = w00 * T.y + w01 * T.z + w10 * BT.y + w11 * BT.z + cb;      \
        float _z2 = w00 * T.z + w01 * T.w + w10 * BT.z + w11 * BT.w + cb;      \
        float _z3 = w00 * T.w + w01 * TE  + w10 * BT.w + w11 * BE  + cb;       \
        float _s0 = __builtin_amdgcn_rcpf(1.0f + __expf(-_z0));                \
        float _s1 = __builtin_amdgcn_rcpf(1.0f + __expf(-_z1));                \
        float _s2 = __builtin_amdgcn_rcpf(1.0f + __expf(-_z2));                \
        float _s3 = wmask * __builtin_amdgcn_rcpf(1.0f + __expf(-_z3));        \
        A0 += _s0 * e0.x + _s1 * e0.y + _s2 * e0.z + _s3 * e0.w;               \
        A1 += _s0 * e1.x + _s1 * e1.y + _s2 * e1.z + _s3 * e1.w;               \
        A2 += _s0 * e2.x + _s1 * e2.y + _s2 * e2.z + _s3 * e2.w;               \
        A3 += _s0 * e3.x + _s1 * e3.y + _s2 * e3.z + _s3 * e3.w;               \
    }

#define ROW_BODY()                                                             \
    {                                                                          \
        float4 bA = *(const float4*)(xA + HW);                                 \
        float4 bB = *(const float4*)(xB + HW);                                 \
        float4 e0 = *(const float4*)(ep0);                                     \
        float4 e1 = *(const float4*)(ep1);                                     \
        float4 e2 = *(const float4*)(ep2);                                     \
        float4 e3 = *(const float4*)(ep3);                                     \
        float teA = __shfl_down(tA.x, 1, 64);                                  \
        float teB = __shfl_down(tB.x, 1, 64);                                  \
        float beA = __shfl_down(bA.x, 1, 64);                                  \
        float beB = __shfl_down(bB.x, 1, 64);                                  \
        CONV4(tA, bA, teA, beA, aA0, aA1, aA2, aA3)                            \
        CONV4(tB, bB, teB, beB, aB0, aB1, aB2, aB3)                            \
        tA = bA; tB = bB;                                                      \
        xA += HW; xB += HW;                                                    \
        ep0 += OW; ep1 += OW; ep2 += OW; ep3 += OW;                            \
    }

__global__ __launch_bounds__(256, 4) void conv_embed_direct(
    const float* __restrict__ x, const float* __restrict__ conv_w,
    const float* __restrict__ conv_b, const float* __restrict__ embed_w,
    float* __restrict__ partial)   // [NCH][NB][4]
{
    const int blk   = blockIdx.x;          // grid = NCH * 128 = 2048
    const int chunk = blk >> 7;            // 0..15
    const int iset  = blk & 127;           // image octet
    const int tid   = threadIdx.x;
    const int wid   = tid >> 6;
    const int lane  = tid & 63;
    const int b     = iset * 8 + wid * 2;  // wave's two images: b, b+1
    const int r0    = chunk * RPC;

    const float w00 = conv_w[0], w01 = conv_w[1];
    const float w10 = conv_w[2], w11 = conv_w[3];
    const float cb  = conv_b[0];

    const int   c4    = (lane < 56) ? (lane << 2) : 220;  // clamped x col
    const int   cg    = (lane < 56) ? lane : 55;          // clamped ew group
    const float wmask = (lane == 55) ? 0.f : 1.f;         // kill col-223 slot

    const float* xA  = x + (size_t)b * IMG + (size_t)r0 * HW + c4;
    const float* xB  = xA + IMG;
    const float* ep0 = embed_w + (size_t)r0 * OW + (cg << 2);
    const float* ep1 = ep0 + FLAT;
    const float* ep2 = ep0 + 2 * FLAT;
    const float* ep3 = ep0 + 3 * FLAT;

    float4 tA = *(const float4*)xA;        // top row of first output row
    float4 tB = *(const float4*)xB;

    float aA0 = 0.f, aA1 = 0.f, aA2 = 0.f, aA3 = 0.f;
    float aB0 = 0.f, aB1 = 0.f, aB2 = 0.f, aB3 = 0.f;

    #pragma unroll 3
    for (int rr = 0; rr < 13; ++rr) ROW_BODY();
    if (chunk != NCH - 1) ROW_BODY();      // chunks 0-14 have 14 rows

    // lanes 56-63 processed clamped/garbage data: drop before reduction
    if (lane >= 56) {
        aA0 = aA1 = aA2 = aA3 = 0.f;
        aB0 = aB1 = aB2 = aB3 = 0.f;
    }

    #pragma unroll
    for (int off = 32; off > 0; off >>= 1) {
        aA0 += __shfl_down(aA0, off, 64);
        aA1 += __shfl_down(aA1, off, 64);
        aA2 += __shfl_down(aA2, off, 64);
        aA3 += __shfl_down(aA3, off, 64);
        aB0 += __shfl_down(aB0, off, 64);
        aB1 += __shfl_down(aB1, off, 64);
        aB2 += __shfl_down(aB2, off, 64);
        aB3 += __shfl_down(aB3, off, 64);
    }
    if (lane == 0) {
        ((float4*)(partial + ((size_t)chunk * NB + b) * 4))[0] =
            make_float4(aA0, aA1, aA2, aA3);
        ((float4*)(partial + ((size_t)chunk * NB + b + 1) * 4))[0] =
            make_float4(aB0, aB1, aB2, aB3);
    }
}

// ---------------------------------------------------------------------------
// Fallback (round-1 style) if ws too small: writes partial[0] (no bias).
// ---------------------------------------------------------------------------
__global__ __launch_bounds__(256) void conv_embed_kernel(
    const float* __restrict__ x, const float* __restrict__ conv_w,
    const float* __restrict__ conv_b, const float* __restrict__ embed_w,
    float* __restrict__ partial)
{
    const int b   = blockIdx.x;
    const int tid = threadIdx.x;
    const float w00 = conv_w[0], w01 = conv_w[1];
    const float w10 = conv_w[2], w11 = conv_w[3];
    const float cb  = conv_b[0];
    const float* __restrict__ xb  = x + (size_t)b * IMG;
    const float* __restrict__ ew0 = embed_w;
    const float* __restrict__ ew1 = embed_w + FLAT;
    const float* __restrict__ ew2 = embed_w + 2 * FLAT;
    const float* __restrict__ ew3 = embed_w + 3 * FLAT;
    float a0 = 0.f, a1 = 0.f, a2 = 0.f, a3 = 0.f;
    for (int p = tid; p < FLAT; p += 256) {
        unsigned up = (unsigned)p;
        unsigned i  = up / 223u;
        unsigned j  = up - i * 223u;
        const float* xr = xb + i * HW + j;
        float z = w00 * xr[0] + w01 * xr[1] + w10 * xr[HW] + w11 * xr[HW + 1] + cb;
        float s = 1.0f / (1.0f + __expf(-z));
        a0 += s * ew0[p]; a1 += s * ew1[p]; a2 += s * ew2[p]; a3 += s * ew3[p];
    }
    #pragma unroll
    for (int off = 32; off > 0; off >>= 1) {
        a0 += __shfl_down(a0, off, 64);
        a1 += __shfl_down(a1, off, 64);
        a2 += __shfl_down(a2, off, 64);
        a3 += __shfl_down(a3, off, 64);
    }
    __shared__ float red[4][4];
    const int wid  = tid >> 6;
    const int lane = tid & 63;
    if (lane == 0) { red[wid][0]=a0; red[wid][1]=a1; red[wid][2]=a2; red[wid][3]=a3; }
    __syncthreads();
    if (tid == 0) {
        float r0 = red[0][0]+red[1][0]+red[2][0]+red[3][0];
        float r1 = red[0][1]+red[1][1]+red[2][1]+red[3][1];
        float r2 = red[0][2]+red[1][2]+red[2][2]+red[3][2];
        float r3 = red[0][3]+red[1][3]+red[2][3]+red[3][3];
        ((float4*)(partial + (size_t)b * 4))[0] = make_float4(r0, r1, r2, r3);
    }
}

// ---------------------------------------------------------------------------
// Kernel 2 (fused): stage = sum NCHP partials + bias -> e, k = e@ent inline;
// then 4-query-row online-softmax attention + mean + sigmoid -> out.
// ---------------------------------------------------------------------------
#define AROW(QR, M, L, A0, A1, A2, A3)                                         \
    {                                                                          \
        float _sc0 = 0.5f * (QR.x * kc.x + QR.y * kc.y + QR.z * kc.z + QR.w * kc.w);\
        float _mn = fmaxf(M, _sc0);                                            \
        float _sc = __expf(M - _mn);                                           \
        float _p  = __expf(_sc0 - _mn);                                        \
        L  = L  * _sc + _p;                                                    \
        A0 = A0 * _sc + _p * ec.x;                                             \
        A1 = A1 * _sc + _p * ec.y;                                             \
        A2 = A2 * _sc + _p * ec.z;                                             \
        A3 = A3 * _sc + _p * ec.w;                                             \
        M = _mn;                                                               \
    }

#define AMERGE(M, L, A0, A1, A2, A3)                                           \
    {                                                                          \
        float _mm = __shfl_down(M,  off, 64);                                  \
        float _ll = __shfl_down(L,  off, 64);                                  \
        float _b0 = __shfl_down(A0, off, 64);                                  \
        float _b1 = __shfl_down(A1, off, 64);                                  \
        float _b2 = __shfl_down(A2, off, 64);                                  \
        float _b3 = __shfl_down(A3, off, 64);                                  \
        float _mn = fmaxf(M, _mm);                                             \
        float _s1 = __expf(M - _mn), _s2 = __expf(_mm - _mn);                  \
        L  = L  * _s1 + _ll * _s2;                                             \
        A0 = A0 * _s1 + _b0 * _s2;                                             \
        A1 = A1 * _s1 + _b1 * _s2;                                             \
        A2 = A2 * _s1 + _b2 * _s2;                                             \
        A3 = A3 * _s1 + _b3 * _s2;                                             \
        M = _mn;                                                               \
    }

template <int NCHP>
__global__ __launch_bounds__(256) void attn_fused_kernel(
    const float* __restrict__ partial, const float* __restrict__ embed_b,
    const float* __restrict__ rot, const float* __restrict__ ent,
    float* __restrict__ out)
{
    __shared__ float4 k_lds[NB];
    __shared__ float4 e_lds[NB];
    __shared__ float  wred[4][4][6];
    const int r0  = blockIdx.x * 4;
    const int tid = threadIdx.x;
    const int wid  = tid >> 6;
    const int lane = tid & 63;

    float rt[16], en[16];
    #pragma unroll
    for (int i = 0; i < 16; ++i) { rt[i] = rot[i]; en[i] = ent[i]; }
    const float b0v = embed_b[0], b1v = embed_b[1];
    const float b2v = embed_b[2], b3v = embed_b[3];

    for (int c = tid; c < NB; c += 256) {
        float s0 = b0v, s1 = b1v, s2 = b2v, s3 = b3v;
        #pragma unroll
        for (int s = 0; s < NCHP; ++s) {
            float4 p = ((const float4*)partial)[(size_t)s * NB + c];
            s0 += p.x; s1 += p.y; s2 += p.z; s3 += p.w;
        }
        e_lds[c] = make_float4(s0, s1, s2, s3);
        k_lds[c] = make_float4(
            s0 * en[0] + s1 * en[4] + s2 * en[8]  + s3 * en[12],
            s0 * en[1] + s1 * en[5] + s2 * en[9]  + s3 * en[13],
            s0 * en[2] + s1 * en[6] + s2 * en[10] + s3 * en[14],
            s0 * en[3] + s1 * en[7] + s2 * en[11] + s3 * en[15]);
    }
    __syncthreads();

    float4 q0, q1, q2, q3;
    {
        float4 e;
        e = e_lds[r0];
        q0 = make_float4(e.x*rt[0]+e.y*rt[4]+e.z*rt[8]+e.w*rt[12],
                         e.x*rt[1]+e.y*rt[5]+e.z*rt[9]+e.w*rt[13],
                         e.x*rt[2]+e.y*rt[6]+e.z*rt[10]+e.w*rt[14],
                         e.x*rt[3]+e.y*rt[7]+e.z*rt[11]+e.w*rt[15]);
        e = e_lds[r0 + 1];
        q1 = make_float4(e.x*rt[0]+e.y*rt[4]+e.z*rt[8]+e.w*rt[12],
                         e.x*rt[1]+e.y*rt[5]+e.z*rt[9]+e.w*rt[13],
                         e.x*rt[2]+e.y*rt[6]+e.z*rt[10]+e.w*rt[14],
                         e.x*rt[3]+e.y*rt[7]+e.z*rt[11]+e.w*rt[15]);
        e = e_lds[r0 + 2];
        q2 = make_float4(e.x*rt[0]+e.y*rt[4]+e.z*rt[8]+e.w*rt[12],
                         e.x*rt[1]+e.y*rt[5]+e.z*rt[9]+e.w*rt[13],
                         e.x*rt[2]+e.y*rt[6]+e.z*rt[10]+e.w*rt[14],
                         e.x*rt[3]+e.y*rt[7]+e.z*rt[11]+e.w*rt[15]);
        e = e_lds[r0 + 3];
        q3 = make_float4(e.x*rt[0]+e.y*rt[4]+e.z*rt[8]+e.w*rt[12],
                         e.x*rt[1]+e.y*rt[5]+e.z*rt[9]+e.w*rt[13],
                         e.x*rt[2]+e.y*rt[6]+e.z*rt[10]+e.w*rt[14],
                         e.x*rt[3]+e.y*rt[7]+e.z*rt[11]+e.w*rt[15]);
    }

    float m0 = -INFINITY, l0 = 0.f, a00 = 0.f, a01 = 0.f, a02 = 0.f, a03 = 0.f;
    float m1 = -INFINITY, l1 = 0.f, a10 = 0.f, a11 = 0.f, a12 = 0.f, a13 = 0.f;
    float m2 = -INFINITY, l2 = 0.f, a20 = 0.f, a21 = 0.f, a22 = 0.f, a23 = 0.f;
    float m3 = -INFINITY, l3 = 0.f, a30 = 0.f, a31 = 0.f, a32 = 0.f, a33 = 0.f;

    #pragma unroll
    for (int it = 0; it < 4; ++it) {
        const int c = it * 256 + tid;
        float4 kc = k_lds[c];
        float4 ec = e_lds[c];
        AROW(q0, m0, l0, a00, a01, a02, a03)
        AROW(q1, m1, l1, a10, a11, a12, a13)
        AROW(q2, m2, l2, a20, a21, a22, a23)
        AROW(q3, m3, l3, a30, a31, a32, a33)
    }

    #pragma unroll
    for (int off = 32; off > 0; off >>= 1) {
        AMERGE(m0, l0, a00, a01, a02, a03)
        AMERGE(m1, l1, a10, a11, a12, a13)
        AMERGE(m2, l2, a20, a21, a22, a23)
        AMERGE(m3, l3, a30, a31, a32, a33)
    }

    if (lane == 0) {
        wred[wid][0][0] = m0;  wred[wid][0][1] = l0;
        wred[wid][0][2] = a00; wred[wid][0][3] = a01;
        wred[wid][0][4] = a02; wred[wid][0][5] = a03;
        wred[wid][1][0] = m1;  wred[wid][1][1] = l1;
        wred[wid][1][2] = a10; wred[wid][1][3] = a11;
        wred[wid][1][4] = a12; wred[wid][1][5] = a13;
        wred[wid][2][0] = m2;  wred[wid][2][1] = l2;
        wred[wid][2][2] = a20; wred[wid][2][3] = a21;
        wred[wid][2][4] = a22; wred[wid][2][5] = a23;
        wred[wid][3][0] = m3;  wred[wid][3][1] = l3;
        wred[wid][3][2] = a30; wred[wid][3][3] = a31;
        wred[wid][3][4] = a32; wred[wid][3][5] = a33;
    }
    __syncthreads();
    if (tid < 4) {
        float M = wred[0][tid][0], L = wred[0][tid][1];
        float A0 = wred[0][tid][2], A1 = wred[0][tid][3];
        float A2 = wred[0][tid][4], A3 = wred[0][tid][5];
        #pragma unroll
        for (int w = 1; w < 4; ++w) {
            float mw = wred[w][tid][0];
            float mn = fmaxf(M, mw);
            float s1 = __expf(M - mn), s2 = __expf(mw - mn);
            L  = L  * s1 + wred[w][tid][1] * s2;
            A0 = A0 * s1 + wred[w][tid][2] * s2;
            A1 = A1 * s1 + wred[w][tid][3] * s2;
            A2 = A2 * s1 + wred[w][tid][4] * s2;
            A3 = A3 * s1 + wred[w][tid][5] * s2;
            M = mn;
        }
        float mean = (A0 + A1 + A2 + A3) / (4.0f * L);
        float prob = 1.0f / (1.0f + __expf(-mean));
        out[(r0 + tid) * 2 + 0] = prob;
        out[(r0 + tid) * 2 + 1] = 1.0f - prob;
    }
}

// ---------------------------------------------------------------------------
extern "C" void kernel_launch(void* const* d_in, const int* in_sizes, int n_in,
                              void* d_out, int out_size, void* d_ws, size_t ws_size,
                              hipStream_t stream) {
    const float* x       = (const float*)d_in[0];
    const float* conv_w  = (const float*)d_in[1];
    const float* conv_b  = (const float*)d_in[2];
    const float* embed_w = (const float*)d_in[3];
    const float* embed_b = (const float*)d_in[4];
    const float* rot     = (const float*)d_in[5];
    const float* ent     = (const float*)d_in[6];
    float* out = (float*)d_out;

    float* partial = (float*)d_ws;                  // NCH*NB*4 floats (256 KB)

    const size_t need = (size_t)(NCH * NB * 4) * sizeof(float);

    if (ws_size >= need) {
        conv_embed_direct<<<NCH * 128, 256, 0, stream>>>(x, conv_w, conv_b,
                                                         embed_w, partial);
        attn_fused_kernel<NCH><<<NB / 4, 256, 0, stream>>>(partial, embed_b,
                                                           rot, ent, out);
    } else {
        conv_embed_kernel<<<NB, 256, 0, stream>>>(x, conv_w, conv_b, embed_w,
                                                  partial);
        attn_fused_kernel<1><<<NB / 4, 256, 0, stream>>>(partial, embed_b,
                                                         rot, ent, out);
    }
}

// Round 17
// 51.762 us; speedup vs baseline: 1.4568x; 1.4568x over previous
//
#include <hip/hip_runtime.h>
#include <math.h>

#define HW    224
#define IMG   (HW * HW)        // 50176
#define OW    223
#define FLAT  (OW * OW)        // 49729
#define NB    1024
#define NCH   8                // row chunks (28,...,27)
#define RPC   28

// ---------------------------------------------------------------------------
// Kernel 1: fused conv+sigmoid+embed, affine row-streaming, DIRECT embed_w
// reads (no pack kernel). Block = (row chunk, 8 images); wave = 2 images,
// lane = col-group. Per body: 2 x float4 + 4 ew float4 (4B-aligned dwordx4,
// row stride 223 = compile-time constant); te/be via shfl. Lane 55's ew .w
// slot is the col-223 garbage -> zero its sigmoid s3 via wmask. Lanes 56-63
// run clamped addresses and are dropped before the reduction.
// NCH=8 (1024 blocks = 4/CU) is the measured optimum: NCH=16 halves
// per-block work and doubles ramp/reduction overhead (75.4 vs 51.8 us).
// ---------------------------------------------------------------------------
#define CONV4(T, BT, TE, BE, A0, A1, A2, A3)                                   \
    {                                                                          \
        float _z0 = w00 * T.x + w01 * T.y + w10 * BT.x + w11 * BT.y + cb;      \
        float _z1 = w00 * T.y + w01 * T.z + w10 * BT.y + w11 * BT.z + cb;      \
        float _z2 = w00 * T.z + w01 * T.w + w10 * BT.z + w11 * BT.w + cb;      \
        float _z3 = w00 * T.w + w01 * TE  + w10 * BT.w + w11 * BE  + cb;       \
        float _s0 = __builtin_amdgcn_rcpf(1.0f + __expf(-_z0));                \
        float _s1 = __builtin_amdgcn_rcpf(1.0f + __expf(-_z1));                \
        float _s2 = __builtin_amdgcn_rcpf(1.0f + __expf(-_z2));                \
        float _s3 = wmask * __builtin_amdgcn_rcpf(1.0f + __expf(-_z3));        \
        A0 += _s0 * e0.x + _s1 * e0.y + _s2 * e0.z + _s3 * e0.w;               \
        A1 += _s0 * e1.x + _s1 * e1.y + _s2 * e1.z + _s3 * e1.w;               \
        A2 += _s0 * e2.x + _s1 * e2.y + _s2 * e2.z + _s3 * e2.w;               \
        A3 += _s0 * e3.x + _s1 * e3.y + _s2 * e3.z + _s3 * e3.w;               \
    }

#define ROW_BODY()                                                             \
    {                                                                          \
        float4 bA = *(const float4*)(xA + HW);                                 \
        float4 bB = *(const float4*)(xB + HW);                                 \
        float4 e0 = *(const float4*)(ep0);                                     \
        float4 e1 = *(const float4*)(ep1);                                     \
        float4 e2 = *(const float4*)(ep2);                                     \
        float4 e3 = *(const float4*)(ep3);                                     \
        float teA = __shfl_down(tA.x, 1, 64);                                  \
        float teB = __shfl_down(tB.x, 1, 64);                                  \
        float beA = __shfl_down(bA.x, 1, 64);                                  \
        float beB = __shfl_down(bB.x, 1, 64);                                  \
        CONV4(tA, bA, teA, beA, aA0, aA1, aA2, aA3)                            \
        CONV4(tB, bB, teB, beB, aB0, aB1, aB2, aB3)                            \
        tA = bA; tB = bB;                                                      \
        xA += HW; xB += HW;                                                    \
        ep0 += OW; ep1 += OW; ep2 += OW; ep3 += OW;                            \
    }

__global__ __launch_bounds__(256, 4) void conv_embed_direct(
    const float* __restrict__ x, const float* __restrict__ conv_w,
    const float* __restrict__ conv_b, const float* __restrict__ embed_w,
    float* __restrict__ partial)   // [NCH][NB][4]
{
    const int blk   = blockIdx.x;          // grid = NCH * 128 = 1024
    const int chunk = blk >> 7;            // 0..7
    const int iset  = blk & 127;           // image octet
    const int tid   = threadIdx.x;
    const int wid   = tid >> 6;
    const int lane  = tid & 63;
    const int b     = iset * 8 + wid * 2;  // wave's two images: b, b+1
    const int r0    = chunk * RPC;

    const float w00 = conv_w[0], w01 = conv_w[1];
    const float w10 = conv_w[2], w11 = conv_w[3];
    const float cb  = conv_b[0];

    const int   c4    = (lane < 56) ? (lane << 2) : 220;  // clamped x col
    const int   cg    = (lane < 56) ? lane : 55;          // clamped ew group
    const float wmask = (lane == 55) ? 0.f : 1.f;         // kill col-223 slot

    const float* xA  = x + (size_t)b * IMG + (size_t)r0 * HW + c4;
    const float* xB  = xA + IMG;
    const float* ep0 = embed_w + (size_t)r0 * OW + (cg << 2);
    const float* ep1 = ep0 + FLAT;
    const float* ep2 = ep0 + 2 * FLAT;
    const float* ep3 = ep0 + 3 * FLAT;

    float4 tA = *(const float4*)xA;        // top row of first output row
    float4 tB = *(const float4*)xB;

    float aA0 = 0.f, aA1 = 0.f, aA2 = 0.f, aA3 = 0.f;
    float aB0 = 0.f, aB1 = 0.f, aB2 = 0.f, aB3 = 0.f;

    #pragma unroll 3
    for (int rr = 0; rr < 27; ++rr) ROW_BODY();
    if (chunk != NCH - 1) ROW_BODY();      // chunks 0-6 have 28 rows

    // lanes 56-63 processed clamped/garbage data: drop before reduction
    if (lane >= 56) {
        aA0 = aA1 = aA2 = aA3 = 0.f;
        aB0 = aB1 = aB2 = aB3 = 0.f;
    }

    #pragma unroll
    for (int off = 32; off > 0; off >>= 1) {
        aA0 += __shfl_down(aA0, off, 64);
        aA1 += __shfl_down(aA1, off, 64);
        aA2 += __shfl_down(aA2, off, 64);
        aA3 += __shfl_down(aA3, off, 64);
        aB0 += __shfl_down(aB0, off, 64);
        aB1 += __shfl_down(aB1, off, 64);
        aB2 += __shfl_down(aB2, off, 64);
        aB3 += __shfl_down(aB3, off, 64);
    }
    if (lane == 0) {
        ((float4*)(partial + ((size_t)chunk * NB + b) * 4))[0] =
            make_float4(aA0, aA1, aA2, aA3);
        ((float4*)(partial + ((size_t)chunk * NB + b + 1) * 4))[0] =
            make_float4(aB0, aB1, aB2, aB3);
    }
}

// ---------------------------------------------------------------------------
// Fallback (round-1 style) if ws too small: writes partial[0] (no bias).
// ---------------------------------------------------------------------------
__global__ __launch_bounds__(256) void conv_embed_kernel(
    const float* __restrict__ x, const float* __restrict__ conv_w,
    const float* __restrict__ conv_b, const float* __restrict__ embed_w,
    float* __restrict__ partial)
{
    const int b   = blockIdx.x;
    const int tid = threadIdx.x;
    const float w00 = conv_w[0], w01 = conv_w[1];
    const float w10 = conv_w[2], w11 = conv_w[3];
    const float cb  = conv_b[0];
    const float* __restrict__ xb  = x + (size_t)b * IMG;
    const float* __restrict__ ew0 = embed_w;
    const float* __restrict__ ew1 = embed_w + FLAT;
    const float* __restrict__ ew2 = embed_w + 2 * FLAT;
    const float* __restrict__ ew3 = embed_w + 3 * FLAT;
    float a0 = 0.f, a1 = 0.f, a2 = 0.f, a3 = 0.f;
    for (int p = tid; p < FLAT; p += 256) {
        unsigned up = (unsigned)p;
        unsigned i  = up / 223u;
        unsigned j  = up - i * 223u;
        const float* xr = xb + i * HW + j;
        float z = w00 * xr[0] + w01 * xr[1] + w10 * xr[HW] + w11 * xr[HW + 1] + cb;
        float s = 1.0f / (1.0f + __expf(-z));
        a0 += s * ew0[p]; a1 += s * ew1[p]; a2 += s * ew2[p]; a3 += s * ew3[p];
    }
    #pragma unroll
    for (int off = 32; off > 0; off >>= 1) {
        a0 += __shfl_down(a0, off, 64);
        a1 += __shfl_down(a1, off, 64);
        a2 += __shfl_down(a2, off, 64);
        a3 += __shfl_down(a3, off, 64);
    }
    __shared__ float red[4][4];
    const int wid  = tid >> 6;
    const int lane = tid & 63;
    if (lane == 0) { red[wid][0]=a0; red[wid][1]=a1; red[wid][2]=a2; red[wid][3]=a3; }
    __syncthreads();
    if (tid == 0) {
        float r0 = red[0][0]+red[1][0]+red[2][0]+red[3][0];
        float r1 = red[0][1]+red[1][1]+red[2][1]+red[3][1];
        float r2 = red[0][2]+red[1][2]+red[2][2]+red[3][2];
        float r3 = red[0][3]+red[1][3]+red[2][3]+red[3][3];
        ((float4*)(partial + (size_t)b * 4))[0] = make_float4(r0, r1, r2, r3);
    }
}

// ---------------------------------------------------------------------------
// Kernel 2 (fused): stage = sum NCHP partials + bias -> e, k = e@ent inline;
// then 4-query-row online-softmax attention + mean + sigmoid -> out.
// ---------------------------------------------------------------------------
#define AROW(QR, M, L, A0, A1, A2, A3)                                         \
    {                                                                          \
        float _sc0 = 0.5f * (QR.x * kc.x + QR.y * kc.y + QR.z * kc.z + QR.w * kc.w);\
        float _mn = fmaxf(M, _sc0);                                            \
        float _sc = __expf(M - _mn);                                           \
        float _p  = __expf(_sc0 - _mn);                                        \
        L  = L  * _sc + _p;                                                    \
        A0 = A0 * _sc + _p * ec.x;                                             \
        A1 = A1 * _sc + _p * ec.y;                                             \
        A2 = A2 * _sc + _p * ec.z;                                             \
        A3 = A3 * _sc + _p * ec.w;                                             \
        M = _mn;                                                               \
    }

#define AMERGE(M, L, A0, A1, A2, A3)                                           \
    {                                                                          \
        float _mm = __shfl_down(M,  off, 64);                                  \
        float _ll = __shfl_down(L,  off, 64);                                  \
        float _b0 = __shfl_down(A0, off, 64);                                  \
        float _b1 = __shfl_down(A1, off, 64);                                  \
        float _b2 = __shfl_down(A2, off, 64);                                  \
        float _b3 = __shfl_down(A3, off, 64);                                  \
        float _mn = fmaxf(M, _mm);                                             \
        float _s1 = __expf(M - _mn), _s2 = __expf(_mm - _mn);                  \
        L  = L  * _s1 + _ll * _s2;                                             \
        A0 = A0 * _s1 + _b0 * _s2;                                             \
        A1 = A1 * _s1 + _b1 * _s2;                                             \
        A2 = A2 * _s1 + _b2 * _s2;                                             \
        A3 = A3 * _s1 + _b3 * _s2;                                             \
        M = _mn;                                                               \
    }

template <int NCHP>
__global__ __launch_bounds__(256) void attn_fused_kernel(
    const float* __restrict__ partial, const float* __restrict__ embed_b,
    const float* __restrict__ rot, const float* __restrict__ ent,
    float* __restrict__ out)
{
    __shared__ float4 k_lds[NB];
    __shared__ float4 e_lds[NB];
    __shared__ float  wred[4][4][6];
    const int r0  = blockIdx.x * 4;
    const int tid = threadIdx.x;
    const int wid  = tid >> 6;
    const int lane = tid & 63;

    float rt[16], en[16];
    #pragma unroll
    for (int i = 0; i < 16; ++i) { rt[i] = rot[i]; en[i] = ent[i]; }
    const float b0v = embed_b[0], b1v = embed_b[1];
    const float b2v = embed_b[2], b3v = embed_b[3];

    for (int c = tid; c < NB; c += 256) {
        float s0 = b0v, s1 = b1v, s2 = b2v, s3 = b3v;
        #pragma unroll
        for (int s = 0; s < NCHP; ++s) {
            float4 p = ((const float4*)partial)[(size_t)s * NB + c];
            s0 += p.x; s1 += p.y; s2 += p.z; s3 += p.w;
        }
        e_lds[c] = make_float4(s0, s1, s2, s3);
        k_lds[c] = make_float4(
            s0 * en[0] + s1 * en[4] + s2 * en[8]  + s3 * en[12],
            s0 * en[1] + s1 * en[5] + s2 * en[9]  + s3 * en[13],
            s0 * en[2] + s1 * en[6] + s2 * en[10] + s3 * en[14],
            s0 * en[3] + s1 * en[7] + s2 * en[11] + s3 * en[15]);
    }
    __syncthreads();

    float4 q0, q1, q2, q3;
    {
        float4 e;
        e = e_lds[r0];
        q0 = make_float4(e.x*rt[0]+e.y*rt[4]+e.z*rt[8]+e.w*rt[12],
                         e.x*rt[1]+e.y*rt[5]+e.z*rt[9]+e.w*rt[13],
                         e.x*rt[2]+e.y*rt[6]+e.z*rt[10]+e.w*rt[14],
                         e.x*rt[3]+e.y*rt[7]+e.z*rt[11]+e.w*rt[15]);
        e = e_lds[r0 + 1];
        q1 = make_float4(e.x*rt[0]+e.y*rt[4]+e.z*rt[8]+e.w*rt[12],
                         e.x*rt[1]+e.y*rt[5]+e.z*rt[9]+e.w*rt[13],
                         e.x*rt[2]+e.y*rt[6]+e.z*rt[10]+e.w*rt[14],
                         e.x*rt[3]+e.y*rt[7]+e.z*rt[11]+e.w*rt[15]);
        e = e_lds[r0 + 2];
        q2 = make_float4(e.x*rt[0]+e.y*rt[4]+e.z*rt[8]+e.w*rt[12],
                         e.x*rt[1]+e.y*rt[5]+e.z*rt[9]+e.w*rt[13],
                         e.x*rt[2]+e.y*rt[6]+e.z*rt[10]+e.w*rt[14],
                         e.x*rt[3]+e.y*rt[7]+e.z*rt[11]+e.w*rt[15]);
        e = e_lds[r0 + 3];
        q3 = make_float4(e.x*rt[0]+e.y*rt[4]+e.z*rt[8]+e.w*rt[12],
                         e.x*rt[1]+e.y*rt[5]+e.z*rt[9]+e.w*rt[13],
                         e.x*rt[2]+e.y*rt[6]+e.z*rt[10]+e.w*rt[14],
                         e.x*rt[3]+e.y*rt[7]+e.z*rt[11]+e.w*rt[15]);
    }

    float m0 = -INFINITY, l0 = 0.f, a00 = 0.f, a01 = 0.f, a02 = 0.f, a03 = 0.f;
    float m1 = -INFINITY, l1 = 0.f, a10 = 0.f, a11 = 0.f, a12 = 0.f, a13 = 0.f;
    float m2 = -INFINITY, l2 = 0.f, a20 = 0.f, a21 = 0.f, a22 = 0.f, a23 = 0.f;
    float m3 = -INFINITY, l3 = 0.f, a30 = 0.f, a31 = 0.f, a32 = 0.f, a33 = 0.f;

    #pragma unroll
    for (int it = 0; it < 4; ++it) {
        const int c = it * 256 + tid;
        float4 kc = k_lds[c];
        float4 ec = e_lds[c];
        AROW(q0, m0, l0, a00, a01, a02, a03)
        AROW(q1, m1, l1, a10, a11, a12, a13)
        AROW(q2, m2, l2, a20, a21, a22, a23)
        AROW(q3, m3, l3, a30, a31, a32, a33)
    }

    #pragma unroll
    for (int off = 32; off > 0; off >>= 1) {
        AMERGE(m0, l0, a00, a01, a02, a03)
        AMERGE(m1, l1, a10, a11, a12, a13)
        AMERGE(m2, l2, a20, a21, a22, a23)
        AMERGE(m3, l3, a30, a31, a32, a33)
    }

    if (lane == 0) {
        wred[wid][0][0] = m0;  wred[wid][0][1] = l0;
        wred[wid][0][2] = a00; wred[wid][0][3] = a01;
        wred[wid][0][4] = a02; wred[wid][0][5] = a03;
        wred[wid][1][0] = m1;  wred[wid][1][1] = l1;
        wred[wid][1][2] = a10; wred[wid][1][3] = a11;
        wred[wid][1][4] = a12; wred[wid][1][5] = a13;
        wred[wid][2][0] = m2;  wred[wid][2][1] = l2;
        wred[wid][2][2] = a20; wred[wid][2][3] = a21;
        wred[wid][2][4] = a22; wred[wid][2][5] = a23;
        wred[wid][3][0] = m3;  wred[wid][3][1] = l3;
        wred[wid][3][2] = a30; wred[wid][3][3] = a31;
        wred[wid][3][4] = a32; wred[wid][3][5] = a33;
    }
    __syncthreads();
    if (tid < 4) {
        float M = wred[0][tid][0], L = wred[0][tid][1];
        float A0 = wred[0][tid][2], A1 = wred[0][tid][3];
        float A2 = wred[0][tid][4], A3 = wred[0][tid][5];
        #pragma unroll
        for (int w = 1; w < 4; ++w) {
            float mw = wred[w][tid][0];
            float mn = fmaxf(M, mw);
            float s1 = __expf(M - mn), s2 = __expf(mw - mn);
            L  = L  * s1 + wred[w][tid][1] * s2;
            A0 = A0 * s1 + wred[w][tid][2] * s2;
            A1 = A1 * s1 + wred[w][tid][3] * s2;
            A2 = A2 * s1 + wred[w][tid][4] * s2;
            A3 = A3 * s1 + wred[w][tid][5] * s2;
            M = mn;
        }
        float mean = (A0 + A1 + A2 + A3) / (4.0f * L);
        float prob = 1.0f / (1.0f + __expf(-mean));
        out[(r0 + tid) * 2 + 0] = prob;
        out[(r0 + tid) * 2 + 1] = 1.0f - prob;
    }
}

// ---------------------------------------------------------------------------
extern "C" void kernel_launch(void* const* d_in, const int* in_sizes, int n_in,
                              void* d_out, int out_size, void* d_ws, size_t ws_size,
                              hipStream_t stream) {
    const float* x       = (const float*)d_in[0];
    const float* conv_w  = (const float*)d_in[1];
    const float* conv_b  = (const float*)d_in[2];
    const float* embed_w = (const float*)d_in[3];
    const float* embed_b = (const float*)d_in[4];
    const float* rot     = (const float*)d_in[5];
    const float* ent     = (const float*)d_in[6];
    float* out = (float*)d_out;

    float* partial = (float*)d_ws;                  // NCH*NB*4 floats (128 KB)

    const size_t need = (size_t)(NCH * NB * 4) * sizeof(float);

    if (ws_size >= need) {
        conv_embed_direct<<<NCH * 128, 256, 0, stream>>>(x, conv_w, conv_b,
                                                         embed_w, partial);
        attn_fused_kernel<NCH><<<NB / 4, 256, 0, stream>>>(partial, embed_b,
                                                           rot, ent, out);
    } else {
        conv_embed_kernel<<<NB, 256, 0, stream>>>(x, conv_w, conv_b, embed_w,
                                                  partial);
        attn_fused_kernel<1><<<NB / 4, 256, 0, stream>>>(partial, embed_b,
                                                         rot, ent, out);
    }
}